// Round 8
// baseline (242.692 us; speedup 1.0000x reference)
//
#include <hip/hip_runtime.h>
#include <hip/hip_bf16.h>

#define IN_FEAT 256
#define HEADS 4
#define OUT_FEAT 64
#define NEG_SLOPE 0.2f

typedef __bf16 bf16x8 __attribute__((ext_vector_type(8)));
typedef float f32x4 __attribute__((ext_vector_type(4)));

__device__ inline unsigned short f2bf(float f) {
    union { float f; unsigned u; } v; v.f = f;
    unsigned r = v.u + 0x7FFF + ((v.u >> 16) & 1);   // RNE, finite inputs
    return (unsigned short)(r >> 16);
}
__device__ inline float bf2f(unsigned short u) {
    union { unsigned u; float f; } v; v.u = ((unsigned)u) << 16; return v.f;
}

// ---------------- CSR build --------------------------------------------------
__global__ void zero_counts(int* __restrict__ counts, int n, int* __restrict__ gcur) {
    int idx = blockIdx.x * blockDim.x + threadIdx.x;
    int stride = gridDim.x * blockDim.x;
    for (int i = idx; i < n; i += stride) counts[i] = 0;
    if (blockIdx.x == 0 && threadIdx.x == 0) *gcur = 0;
}

__global__ void hist_kernel(const int* __restrict__ ei, int* __restrict__ counts,
                            int E, int N) {
    int idx = blockIdx.x * blockDim.x + threadIdx.x;
    int stride = gridDim.x * blockDim.x;
    for (int e = idx; e < E; e += stride) {
        int d = ei[E + e];
        if ((unsigned)d < (unsigned)N) atomicAdd(&counts[d], 1);
    }
}

// Parallel scan: per-1024 tile local scan + one atomicAdd to reserve the base.
__global__ __launch_bounds__(1024) void scan_atomic(const int* __restrict__ counts,
                                                    int* __restrict__ offsets,
                                                    int* __restrict__ cursor,
                                                    int* __restrict__ gcur, int N) {
    __shared__ int sdata[1024];
    __shared__ int sbase;
    const int t = threadIdx.x;
    const int i = blockIdx.x * 1024 + t;
    const int v = (i < N) ? counts[i] : 0;
    sdata[t] = v;
    __syncthreads();
    for (int off = 1; off < 1024; off <<= 1) {
        int u = (t >= off) ? sdata[t - off] : 0;
        __syncthreads();
        sdata[t] += u;
        __syncthreads();
    }
    if (t == 1023) sbase = atomicAdd(gcur, sdata[1023]);
    __syncthreads();
    if (i < N) {
        int excl = sbase + sdata[t] - v;
        offsets[i] = excl;
        cursor[i] = excl;
    }
}

__global__ void scatter_kernel(const int* __restrict__ ei, int* __restrict__ cursor,
                               int* __restrict__ sorted_src, int E, int N) {
    int idx = blockIdx.x * blockDim.x + threadIdx.x;
    int stride = gridDim.x * blockDim.x;
    for (int e = idx; e < E; e += stride) {
        int s = ei[e];
        int d = ei[E + e];
        if ((unsigned)s >= (unsigned)N || (unsigned)d >= (unsigned)N) continue;
        int pos = atomicAdd(&cursor[d], 1);
        sorted_src[pos] = s;
    }
}

// ---------------- X -> Xb (bf16, pre-swizzled), W -> Wtb (transposed bf16, pre-swizzled)
// Chunk c (16B, 8 bf16) of K-group g in row r stored at position c ^ (r&7).
__global__ void cvt_xw(const float* __restrict__ X, const float* __restrict__ W,
                       unsigned short* __restrict__ Xb, unsigned short* __restrict__ Wtb,
                       int N) {
    const int totalX = N * 32;            // 16B chunks of Xb
    const int total = totalX + 256 * 32;  // + Wtb chunks
    int idx = blockIdx.x * blockDim.x + threadIdx.x;
    if (idx >= total) return;
    if (idx < totalX) {
        int r = idx >> 5, j = idx & 31;
        int g = j >> 3, c = j & 7;
        const float4 v0 = *reinterpret_cast<const float4*>(&X[(size_t)r * 256 + j * 8]);
        const float4 v1 = *reinterpret_cast<const float4*>(&X[(size_t)r * 256 + j * 8 + 4]);
        ushort4 p0, p1;
        p0.x = f2bf(v0.x); p0.y = f2bf(v0.y); p0.z = f2bf(v0.z); p0.w = f2bf(v0.w);
        p1.x = f2bf(v1.x); p1.y = f2bf(v1.y); p1.z = f2bf(v1.z); p1.w = f2bf(v1.w);
        unsigned short* dst = &Xb[(size_t)r * 256 + (g * 8 + (c ^ (r & 7))) * 8];
        *reinterpret_cast<ushort4*>(dst) = p0;
        *reinterpret_cast<ushort4*>(dst + 4) = p1;
    } else {
        int t = idx - totalX;
        int n = t >> 5, j = t & 31;
        int g = j >> 3, c = j & 7;
        ushort4 p0, p1;
        p0.x = f2bf(W[(size_t)(j * 8 + 0) * 256 + n]);
        p0.y = f2bf(W[(size_t)(j * 8 + 1) * 256 + n]);
        p0.z = f2bf(W[(size_t)(j * 8 + 2) * 256 + n]);
        p0.w = f2bf(W[(size_t)(j * 8 + 3) * 256 + n]);
        p1.x = f2bf(W[(size_t)(j * 8 + 4) * 256 + n]);
        p1.y = f2bf(W[(size_t)(j * 8 + 5) * 256 + n]);
        p1.z = f2bf(W[(size_t)(j * 8 + 6) * 256 + n]);
        p1.w = f2bf(W[(size_t)(j * 8 + 7) * 256 + n]);
        unsigned short* dst = &Wtb[(size_t)n * 256 + (g * 8 + (c ^ (n & 7))) * 8];
        *reinterpret_cast<ushort4*>(dst) = p0;
        *reinterpret_cast<ushort4*>(dst + 4) = p1;
    }
}

// ---------------- Hb = bf16(Xb @ Wtb^T), fused per-head logits --------------
// 64x256 tile (all heads), BK=64, 4 waves as 2(m)x2(n); wave-tile 32x128.
__global__ __launch_bounds__(256) void gemm_mfma(const unsigned short* __restrict__ Xb,
                                                 const unsigned short* __restrict__ Wtb,
                                                 const float* __restrict__ att_src,
                                                 const float* __restrict__ att_dst,
                                                 unsigned short* __restrict__ Hb,
                                                 float* __restrict__ asrc,
                                                 float* __restrict__ adst, int M) {
    __shared__ __align__(16) unsigned short sA[64 * 64];    // 8 KB
    __shared__ __align__(16) unsigned short sB[256 * 64];   // 32 KB
    const int brow = blockIdx.x * 64;
    const int tid = threadIdx.x;
    const int lane = tid & 63;
    const int wid = tid >> 6;
    const int wr = wid >> 1;          // 0..1 row half
    const int wc = wid & 1;           // 0..1 col half (2 heads each)
    const uint4* Xb4 = reinterpret_cast<const uint4*>(Xb);
    const uint4* Wtb4 = reinterpret_cast<const uint4*>(Wtb);
    uint4* sA4 = reinterpret_cast<uint4*>(sA);
    uint4* sB4 = reinterpret_cast<uint4*>(sB);

    f32x4 acc[2][8] = {};
    uint4 ra[2], rb[8];

    // row stride = 32 uint4 (256 bf16), K-group stride = 8 uint4 (64 bf16)
#define LOADG(g)                                                                  \
    {                                                                             \
        _Pragma("unroll")                                                         \
        for (int i = 0; i < 2; ++i) {                                             \
            int ci = tid + i * 256;                                               \
            ra[i] = Xb4[(size_t)(brow + (ci >> 3)) * 32 + (g) * 8 + (ci & 7)];    \
        }                                                                         \
        _Pragma("unroll")                                                         \
        for (int j = 0; j < 8; ++j) {                                             \
            int ci = tid + j * 256;                                               \
            rb[j] = Wtb4[(size_t)(ci >> 3) * 32 + (g) * 8 + (ci & 7)];            \
        }                                                                         \
    }

    LOADG(0);
    for (int g = 0; g < 4; ++g) {
        if (g) __syncthreads();       // previous step's ds_reads done
        sA4[tid] = ra[0];
        sA4[tid + 256] = ra[1];
#pragma unroll
        for (int j = 0; j < 8; ++j) sB4[tid + j * 256] = rb[j];
        __syncthreads();
        if (g < 3) LOADG(g + 1);      // latency hidden under MFMAs below
#pragma unroll
        for (int kk = 0; kk < 2; ++kk) {
            bf16x8 af[2], bfr[8];
            const int c = kk * 4 + (lane >> 4);
#pragma unroll
            for (int m = 0; m < 2; ++m) {
                int r = wr * 32 + m * 16 + (lane & 15);
                af[m] = *reinterpret_cast<const bf16x8*>(&sA[r * 64 + ((c ^ (r & 7)) << 3)]);
            }
#pragma unroll
            for (int nf = 0; nf < 8; ++nf) {
                int n = wc * 128 + nf * 16 + (lane & 15);
                bfr[nf] = *reinterpret_cast<const bf16x8*>(&sB[n * 64 + ((c ^ (n & 7)) << 3)]);
            }
#pragma unroll
            for (int m = 0; m < 2; ++m)
#pragma unroll
                for (int nf = 0; nf < 8; ++nf)
                    acc[m][nf] = __builtin_amdgcn_mfma_f32_16x16x32_bf16(
                        af[m], bfr[nf], acc[m][nf], 0, 0, 0);
        }
    }
#undef LOADG

    // ---- epilogue: bf16 store + fused logits for this wave's 2 heads ----
    float attS[8], attD[8];
#pragma unroll
    for (int nf = 0; nf < 8; ++nf) {
        int col = wc * 128 + nf * 16 + (lane & 15);
        attS[nf] = att_src[col];
        attD[nf] = att_dst[col];
    }
#pragma unroll
    for (int m = 0; m < 2; ++m)
#pragma unroll
        for (int i = 0; i < 4; ++i) {
            int R = brow + wr * 32 + m * 16 + ((lane >> 4) << 2) + i;
            float p0s = 0.f, p0d = 0.f, p1s = 0.f, p1d = 0.f;
#pragma unroll
            for (int nf = 0; nf < 8; ++nf) {
                float v = acc[m][nf][i];
                if (nf < 4) { p0s += v * attS[nf]; p0d += v * attD[nf]; }
                else        { p1s += v * attS[nf]; p1d += v * attD[nf]; }
                if (R < M)
                    Hb[(size_t)R * 256 + wc * 128 + nf * 16 + (lane & 15)] = f2bf(v);
            }
#pragma unroll
            for (int off = 1; off < 16; off <<= 1) {
                p0s += __shfl_xor(p0s, off, 64);
                p0d += __shfl_xor(p0d, off, 64);
                p1s += __shfl_xor(p1s, off, 64);
                p1d += __shfl_xor(p1d, off, 64);
            }
            if ((lane & 15) == 0 && R < M) {
                int h0 = wc * 2;
                asrc[R * HEADS + h0]     = p0s;
                asrc[R * HEADS + h0 + 1] = p1s;
                adst[R * HEADS + h0]     = p0d;
                adst[R * HEADS + h0 + 1] = p1d;
            }
        }
}

// ---------------- gather aggregate: one wave per destination node -----------
__global__ __launch_bounds__(256) void aggregate(const unsigned short* __restrict__ Hb,
                                                 const float* __restrict__ asrc,
                                                 const float* __restrict__ adst,
                                                 const int* __restrict__ offsets,
                                                 const int* __restrict__ counts,
                                                 const int* __restrict__ sorted_src,
                                                 const float* __restrict__ bias,
                                                 float* __restrict__ out, int N) {
    int gtid = blockIdx.x * blockDim.x + threadIdx.x;
    int wave = gtid >> 6;
    int lane = threadIdx.x & 63;
    int nwaves = (gridDim.x * blockDim.x) >> 6;
    int head = lane >> 4;
    const float4 bv = *reinterpret_cast<const float4*>(&bias[lane * 4]);
    for (int d = wave; d < N; d += nwaves) {
        const float ad = adst[d * HEADS + head];
        float a = asrc[d * HEADS + head] + ad;
        float w = __expf((a > 0.f) ? a : NEG_SLOPE * a);
        ushort4 ud = *reinterpret_cast<const ushort4*>(&Hb[(size_t)d * IN_FEAT + lane * 4]);
        float4 acc = make_float4(w * bf2f(ud.x), w * bf2f(ud.y),
                                 w * bf2f(ud.z), w * bf2f(ud.w));
        float den = w;
        const int start = offsets[d];
        const int cnt = counts[d];
        int k = 0;
        for (; k + 3 < cnt; k += 4) {
            int s0 = sorted_src[start + k + 0];
            int s1 = sorted_src[start + k + 1];
            int s2 = sorted_src[start + k + 2];
            int s3 = sorted_src[start + k + 3];
            float a0 = asrc[s0 * HEADS + head] + ad;
            float a1 = asrc[s1 * HEADS + head] + ad;
            float a2 = asrc[s2 * HEADS + head] + ad;
            float a3 = asrc[s3 * HEADS + head] + ad;
            ushort4 u0 = *reinterpret_cast<const ushort4*>(&Hb[(size_t)s0 * IN_FEAT + lane * 4]);
            ushort4 u1 = *reinterpret_cast<const ushort4*>(&Hb[(size_t)s1 * IN_FEAT + lane * 4]);
            ushort4 u2 = *reinterpret_cast<const ushort4*>(&Hb[(size_t)s2 * IN_FEAT + lane * 4]);
            ushort4 u3 = *reinterpret_cast<const ushort4*>(&Hb[(size_t)s3 * IN_FEAT + lane * 4]);
            float w0 = __expf((a0 > 0.f) ? a0 : NEG_SLOPE * a0);
            float w1 = __expf((a1 > 0.f) ? a1 : NEG_SLOPE * a1);
            float w2 = __expf((a2 > 0.f) ? a2 : NEG_SLOPE * a2);
            float w3 = __expf((a3 > 0.f) ? a3 : NEG_SLOPE * a3);
            acc.x += w0 * bf2f(u0.x) + w1 * bf2f(u1.x) + w2 * bf2f(u2.x) + w3 * bf2f(u3.x);
            acc.y += w0 * bf2f(u0.y) + w1 * bf2f(u1.y) + w2 * bf2f(u2.y) + w3 * bf2f(u3.y);
            acc.z += w0 * bf2f(u0.z) + w1 * bf2f(u1.z) + w2 * bf2f(u2.z) + w3 * bf2f(u3.z);
            acc.w += w0 * bf2f(u0.w) + w1 * bf2f(u1.w) + w2 * bf2f(u2.w) + w3 * bf2f(u3.w);
            den += w0 + w1 + w2 + w3;
        }
        for (; k < cnt; ++k) {
            int s0 = sorted_src[start + k];
            float a0 = asrc[s0 * HEADS + head] + ad;
            ushort4 u0 = *reinterpret_cast<const ushort4*>(&Hb[(size_t)s0 * IN_FEAT + lane * 4]);
            float w0 = __expf((a0 > 0.f) ? a0 : NEG_SLOPE * a0);
            acc.x += w0 * bf2f(u0.x);
            acc.y += w0 * bf2f(u0.y);
            acc.z += w0 * bf2f(u0.z);
            acc.w += w0 * bf2f(u0.w);
            den += w0;
        }
        const float inv = 1.f / den;
        float4 r;
        r.x = fmaxf(acc.x * inv + bv.x, 0.f);
        r.y = fmaxf(acc.y * inv + bv.y, 0.f);
        r.z = fmaxf(acc.z * inv + bv.z, 0.f);
        r.w = fmaxf(acc.w * inv + bv.w, 0.f);
        *reinterpret_cast<float4*>(&out[(size_t)d * IN_FEAT + lane * 4]) = r;
    }
}

extern "C" void kernel_launch(void* const* d_in, const int* in_sizes, int n_in,
                              void* d_out, int out_size, void* d_ws, size_t ws_size,
                              hipStream_t stream) {
    const float* x       = (const float*)d_in[0];
    const int*   ei      = (const int*)d_in[1];      // harness converts int64 -> int32
    const float* W       = (const float*)d_in[2];
    const float* att_src = (const float*)d_in[3];
    const float* att_dst = (const float*)d_in[4];
    const float* bias    = (const float*)d_in[5];
    float*       out     = (float*)d_out;

    const int N = in_sizes[0] / IN_FEAT;   // 50000
    const int E = in_sizes[1] / 2;         // 800000
    const int Npad = (N + 63) & ~63;       // 50048

    // workspace layout
    unsigned short* Xb = (unsigned short*)d_ws;               // Npad*256 bf16
    unsigned short* Hb = Xb + (size_t)Npad * IN_FEAT;         // Npad*256 bf16
    float* asrc       = (float*)(Hb + (size_t)Npad * IN_FEAT);
    float* adst       = asrc + (size_t)N * HEADS;
    int*   counts     = (int*)(adst + (size_t)N * HEADS);
    int*   offsets    = counts + N;
    int*   cursor     = offsets + N;
    int*   sorted_src = cursor + N;                           // E
    int*   gcur       = sorted_src + E;                       // 4 ints
    unsigned short* Wtb = (unsigned short*)(gcur + 4);        // 256*256 bf16

    // CSR build
    zero_counts<<<256, 256, 0, stream>>>(counts, N, gcur);
    hist_kernel<<<2048, 256, 0, stream>>>(ei, counts, E, N);
    scan_atomic<<<(N + 1023) / 1024, 1024, 0, stream>>>(counts, offsets, cursor, gcur, N);
    scatter_kernel<<<2048, 256, 0, stream>>>(ei, cursor, sorted_src, E, N);

    // bf16 pre-convert (pre-swizzled) + projection + fused logits
    {
        int total = N * 32 + 256 * 32;
        cvt_xw<<<(total + 255) / 256, 256, 0, stream>>>(x, W, Xb, Wtb, N);
    }
    gemm_mfma<<<Npad / 64, 256, 0, stream>>>(Xb, Wtb, att_src, att_dst, Hb, asrc, adst, N);

    // gather aggregation (no atomics)
    aggregate<<<(N * 64 + 255) / 256, 256, 0, stream>>>(Hb, asrc, adst, offsets, counts,
                                                        sorted_src, bias, out, N);
}

// Round 9
// 242.298 us; speedup vs baseline: 1.0016x; 1.0016x over previous
//
#include <hip/hip_runtime.h>
#include <hip/hip_bf16.h>

#define IN_FEAT 256
#define HEADS 4
#define OUT_FEAT 64
#define NEG_SLOPE 0.2f

typedef __bf16 bf16x8 __attribute__((ext_vector_type(8)));
typedef float f32x4 __attribute__((ext_vector_type(4)));

__device__ inline unsigned short f2bf(float f) {
    union { float f; unsigned u; } v; v.f = f;
    unsigned r = v.u + 0x7FFF + ((v.u >> 16) & 1);   // RNE, finite inputs
    return (unsigned short)(r >> 16);
}
__device__ inline float bf2f(unsigned short u) {
    union { unsigned u; float f; } v; v.u = ((unsigned)u) << 16; return v.f;
}

// ---------------- CSR build --------------------------------------------------
__global__ void zero_counts(int* __restrict__ counts, int n, int* __restrict__ gcur) {
    int idx = blockIdx.x * blockDim.x + threadIdx.x;
    int stride = gridDim.x * blockDim.x;
    for (int i = idx; i < n; i += stride) counts[i] = 0;
    if (blockIdx.x == 0 && threadIdx.x == 0) *gcur = 0;
}

__global__ void hist_kernel(const int* __restrict__ ei, int* __restrict__ counts,
                            int E, int N) {
    int idx = blockIdx.x * blockDim.x + threadIdx.x;
    int stride = gridDim.x * blockDim.x;
    for (int e = idx; e < E; e += stride) {
        int d = ei[E + e];
        if ((unsigned)d < (unsigned)N) atomicAdd(&counts[d], 1);
    }
}

// Parallel scan: per-1024 tile local scan + one atomicAdd to reserve the base.
__global__ __launch_bounds__(1024) void scan_atomic(const int* __restrict__ counts,
                                                    int* __restrict__ offsets,
                                                    int* __restrict__ cursor,
                                                    int* __restrict__ gcur, int N) {
    __shared__ int sdata[1024];
    __shared__ int sbase;
    const int t = threadIdx.x;
    const int i = blockIdx.x * 1024 + t;
    const int v = (i < N) ? counts[i] : 0;
    sdata[t] = v;
    __syncthreads();
    for (int off = 1; off < 1024; off <<= 1) {
        int u = (t >= off) ? sdata[t - off] : 0;
        __syncthreads();
        sdata[t] += u;
        __syncthreads();
    }
    if (t == 1023) sbase = atomicAdd(gcur, sdata[1023]);
    __syncthreads();
    if (i < N) {
        int excl = sbase + sdata[t] - v;
        offsets[i] = excl;
        cursor[i] = excl;
    }
}

__global__ void scatter_kernel(const int* __restrict__ ei, int* __restrict__ cursor,
                               int* __restrict__ sorted_src, int E, int N) {
    int idx = blockIdx.x * blockDim.x + threadIdx.x;
    int stride = gridDim.x * blockDim.x;
    for (int e = idx; e < E; e += stride) {
        int s = ei[e];
        int d = ei[E + e];
        if ((unsigned)s >= (unsigned)N || (unsigned)d >= (unsigned)N) continue;
        int pos = atomicAdd(&cursor[d], 1);
        sorted_src[pos] = s;
    }
}

// ---------------- X -> Xb (bf16, pre-swizzled), W -> Wtb (transposed bf16, pre-swizzled)
// Chunk c (16B, 8 bf16) of K-group g in row r stored at position c ^ (r&7).
__global__ void cvt_xw(const float* __restrict__ X, const float* __restrict__ W,
                       unsigned short* __restrict__ Xb, unsigned short* __restrict__ Wtb,
                       int N) {
    const int totalX = N * 32;            // 16B chunks of Xb
    const int total = totalX + 256 * 32;  // + Wtb chunks
    int idx = blockIdx.x * blockDim.x + threadIdx.x;
    if (idx >= total) return;
    if (idx < totalX) {
        int r = idx >> 5, j = idx & 31;
        int g = j >> 3, c = j & 7;
        const float4 v0 = *reinterpret_cast<const float4*>(&X[(size_t)r * 256 + j * 8]);
        const float4 v1 = *reinterpret_cast<const float4*>(&X[(size_t)r * 256 + j * 8 + 4]);
        ushort4 p0, p1;
        p0.x = f2bf(v0.x); p0.y = f2bf(v0.y); p0.z = f2bf(v0.z); p0.w = f2bf(v0.w);
        p1.x = f2bf(v1.x); p1.y = f2bf(v1.y); p1.z = f2bf(v1.z); p1.w = f2bf(v1.w);
        unsigned short* dst = &Xb[(size_t)r * 256 + (g * 8 + (c ^ (r & 7))) * 8];
        *reinterpret_cast<ushort4*>(dst) = p0;
        *reinterpret_cast<ushort4*>(dst + 4) = p1;
    } else {
        int t = idx - totalX;
        int n = t >> 5, j = t & 31;
        int g = j >> 3, c = j & 7;
        ushort4 p0, p1;
        p0.x = f2bf(W[(size_t)(j * 8 + 0) * 256 + n]);
        p0.y = f2bf(W[(size_t)(j * 8 + 1) * 256 + n]);
        p0.z = f2bf(W[(size_t)(j * 8 + 2) * 256 + n]);
        p0.w = f2bf(W[(size_t)(j * 8 + 3) * 256 + n]);
        p1.x = f2bf(W[(size_t)(j * 8 + 4) * 256 + n]);
        p1.y = f2bf(W[(size_t)(j * 8 + 5) * 256 + n]);
        p1.z = f2bf(W[(size_t)(j * 8 + 6) * 256 + n]);
        p1.w = f2bf(W[(size_t)(j * 8 + 7) * 256 + n]);
        unsigned short* dst = &Wtb[(size_t)n * 256 + (g * 8 + (c ^ (n & 7))) * 8];
        *reinterpret_cast<ushort4*>(dst) = p0;
        *reinterpret_cast<ushort4*>(dst + 4) = p1;
    }
}

// ---------------- Hb = bf16(Xb @ Wtb^T), fused per-head logits --------------
// 64x256 tile (all heads), BK=64, 4 waves as 2(m)x2(n); wave-tile 32x128.
// Epilogue stages C through LDS -> full-line global stores (no partial-line RMW).
__global__ __launch_bounds__(256) void gemm_mfma(const unsigned short* __restrict__ Xb,
                                                 const unsigned short* __restrict__ Wtb,
                                                 const float* __restrict__ att_src,
                                                 const float* __restrict__ att_dst,
                                                 unsigned short* __restrict__ Hb,
                                                 float* __restrict__ asrc,
                                                 float* __restrict__ adst, int M) {
    __shared__ __align__(16) unsigned short sMem[64 * 64 + 256 * 64]; // 40 KB
    unsigned short* sA = sMem;            // 64x64
    unsigned short* sB = sMem + 64 * 64;  // 256x64
    unsigned short* sC = sMem;            // 64x256 (reused after K-loop)
    const int brow = blockIdx.x * 64;
    const int tid = threadIdx.x;
    const int lane = tid & 63;
    const int wid = tid >> 6;
    const int wr = wid >> 1;          // 0..1 row half
    const int wc = wid & 1;           // 0..1 col half (2 heads each)
    const uint4* Xb4 = reinterpret_cast<const uint4*>(Xb);
    const uint4* Wtb4 = reinterpret_cast<const uint4*>(Wtb);
    uint4* sA4 = reinterpret_cast<uint4*>(sA);
    uint4* sB4 = reinterpret_cast<uint4*>(sB);

    f32x4 acc[2][8] = {};
    uint4 ra[2], rb[8];

    // row stride = 32 uint4 (256 bf16), K-group stride = 8 uint4 (64 bf16)
#define LOADG(g)                                                                  \
    {                                                                             \
        _Pragma("unroll")                                                         \
        for (int i = 0; i < 2; ++i) {                                             \
            int ci = tid + i * 256;                                               \
            ra[i] = Xb4[(size_t)(brow + (ci >> 3)) * 32 + (g) * 8 + (ci & 7)];    \
        }                                                                         \
        _Pragma("unroll")                                                         \
        for (int j = 0; j < 8; ++j) {                                             \
            int ci = tid + j * 256;                                               \
            rb[j] = Wtb4[(size_t)(ci >> 3) * 32 + (g) * 8 + (ci & 7)];            \
        }                                                                         \
    }

    LOADG(0);
    for (int g = 0; g < 4; ++g) {
        if (g) __syncthreads();       // previous step's ds_reads done
        sA4[tid] = ra[0];
        sA4[tid + 256] = ra[1];
#pragma unroll
        for (int j = 0; j < 8; ++j) sB4[tid + j * 256] = rb[j];
        __syncthreads();
        if (g < 3) LOADG(g + 1);      // latency hidden under MFMAs below
#pragma unroll
        for (int kk = 0; kk < 2; ++kk) {
            bf16x8 af[2], bfr[8];
            const int c = kk * 4 + (lane >> 4);
#pragma unroll
            for (int m = 0; m < 2; ++m) {
                int r = wr * 32 + m * 16 + (lane & 15);
                af[m] = *reinterpret_cast<const bf16x8*>(&sA[r * 64 + ((c ^ (r & 7)) << 3)]);
            }
#pragma unroll
            for (int nf = 0; nf < 8; ++nf) {
                int n = wc * 128 + nf * 16 + (lane & 15);
                bfr[nf] = *reinterpret_cast<const bf16x8*>(&sB[n * 64 + ((c ^ (n & 7)) << 3)]);
            }
#pragma unroll
            for (int m = 0; m < 2; ++m)
#pragma unroll
                for (int nf = 0; nf < 8; ++nf)
                    acc[m][nf] = __builtin_amdgcn_mfma_f32_16x16x32_bf16(
                        af[m], bfr[nf], acc[m][nf], 0, 0, 0);
        }
    }
#undef LOADG

    // ---- fused logits from fragments (register-only + shuffles) ----
    float attS[8], attD[8];
#pragma unroll
    for (int nf = 0; nf < 8; ++nf) {
        int col = wc * 128 + nf * 16 + (lane & 15);
        attS[nf] = att_src[col];
        attD[nf] = att_dst[col];
    }
    __syncthreads();   // all sB reads done; sC may overwrite sA/sB region
#pragma unroll
    for (int m = 0; m < 2; ++m)
#pragma unroll
        for (int i = 0; i < 4; ++i) {
            int rl = wr * 32 + m * 16 + ((lane >> 4) << 2) + i;   // local row
            int R = brow + rl;
            float p0s = 0.f, p0d = 0.f, p1s = 0.f, p1d = 0.f;
            const int swz = (rl >> 2) & 3;
#pragma unroll
            for (int nf = 0; nf < 8; ++nf) {
                float v = acc[m][nf][i];
                if (nf < 4) { p0s += v * attS[nf]; p0d += v * attD[nf]; }
                else        { p1s += v * attS[nf]; p1d += v * attD[nf]; }
                // C-tile staged in LDS: 32B-chunk index swizzled by (rl>>2)&3
                int chunk = wc * 8 + nf;
                sC[rl * 256 + ((chunk ^ swz) << 4) + (lane & 15)] = f2bf(v);
            }
#pragma unroll
            for (int off = 1; off < 16; off <<= 1) {
                p0s += __shfl_xor(p0s, off, 64);
                p0d += __shfl_xor(p0d, off, 64);
                p1s += __shfl_xor(p1s, off, 64);
                p1d += __shfl_xor(p1d, off, 64);
            }
            if ((lane & 15) == 0 && R < M) {
                int h0 = wc * 2;
                asrc[R * HEADS + h0]     = p0s;
                asrc[R * HEADS + h0 + 1] = p1s;
                adst[R * HEADS + h0]     = p0d;
                adst[R * HEADS + h0 + 1] = p1d;
            }
        }
    __syncthreads();
    // ---- coalesced store: 8 passes, 16B per thread, full 512B rows ----
#pragma unroll
    for (int it = 0; it < 8; ++it) {
        int gc = it * 256 + tid;          // 16B chunk id, 32 per row
        int r = gc >> 5;
        int j = gc & 31;
        int cs = (j >> 1) ^ ((r >> 2) & 3);
        const uint4 v = *reinterpret_cast<const uint4*>(
            &sC[r * 256 + (cs << 4) + (j & 1) * 8]);
        if (brow + r < M)
            *reinterpret_cast<uint4*>(&Hb[(size_t)(brow + r) * 256 + j * 8]) = v;
    }
}

// ---------------- gather aggregate: one wave per destination node -----------
__global__ __launch_bounds__(256) void aggregate(const unsigned short* __restrict__ Hb,
                                                 const float* __restrict__ asrc,
                                                 const float* __restrict__ adst,
                                                 const int* __restrict__ offsets,
                                                 const int* __restrict__ counts,
                                                 const int* __restrict__ sorted_src,
                                                 const float* __restrict__ bias,
                                                 float* __restrict__ out, int N) {
    int gtid = blockIdx.x * blockDim.x + threadIdx.x;
    int wave = gtid >> 6;
    int lane = threadIdx.x & 63;
    int nwaves = (gridDim.x * blockDim.x) >> 6;
    int head = lane >> 4;
    const float4 bv = *reinterpret_cast<const float4*>(&bias[lane * 4]);
    for (int d = wave; d < N; d += nwaves) {
        const float ad = adst[d * HEADS + head];
        float a = asrc[d * HEADS + head] + ad;
        float w = __expf((a > 0.f) ? a : NEG_SLOPE * a);
        ushort4 ud = *reinterpret_cast<const ushort4*>(&Hb[(size_t)d * IN_FEAT + lane * 4]);
        float4 acc = make_float4(w * bf2f(ud.x), w * bf2f(ud.y),
                                 w * bf2f(ud.z), w * bf2f(ud.w));
        float den = w;
        const int start = offsets[d];
        const int cnt = counts[d];
        int k = 0;
        for (; k + 3 < cnt; k += 4) {
            int s0 = sorted_src[start + k + 0];
            int s1 = sorted_src[start + k + 1];
            int s2 = sorted_src[start + k + 2];
            int s3 = sorted_src[start + k + 3];
            float a0 = asrc[s0 * HEADS + head] + ad;
            float a1 = asrc[s1 * HEADS + head] + ad;
            float a2 = asrc[s2 * HEADS + head] + ad;
            float a3 = asrc[s3 * HEADS + head] + ad;
            ushort4 u0 = *reinterpret_cast<const ushort4*>(&Hb[(size_t)s0 * IN_FEAT + lane * 4]);
            ushort4 u1 = *reinterpret_cast<const ushort4*>(&Hb[(size_t)s1 * IN_FEAT + lane * 4]);
            ushort4 u2 = *reinterpret_cast<const ushort4*>(&Hb[(size_t)s2 * IN_FEAT + lane * 4]);
            ushort4 u3 = *reinterpret_cast<const ushort4*>(&Hb[(size_t)s3 * IN_FEAT + lane * 4]);
            float w0 = __expf((a0 > 0.f) ? a0 : NEG_SLOPE * a0);
            float w1 = __expf((a1 > 0.f) ? a1 : NEG_SLOPE * a1);
            float w2 = __expf((a2 > 0.f) ? a2 : NEG_SLOPE * a2);
            float w3 = __expf((a3 > 0.f) ? a3 : NEG_SLOPE * a3);
            acc.x += w0 * bf2f(u0.x) + w1 * bf2f(u1.x) + w2 * bf2f(u2.x) + w3 * bf2f(u3.x);
            acc.y += w0 * bf2f(u0.y) + w1 * bf2f(u1.y) + w2 * bf2f(u2.y) + w3 * bf2f(u3.y);
            acc.z += w0 * bf2f(u0.z) + w1 * bf2f(u1.z) + w2 * bf2f(u2.z) + w3 * bf2f(u3.z);
            acc.w += w0 * bf2f(u0.w) + w1 * bf2f(u1.w) + w2 * bf2f(u2.w) + w3 * bf2f(u3.w);
            den += w0 + w1 + w2 + w3;
        }
        for (; k < cnt; ++k) {
            int s0 = sorted_src[start + k];
            float a0 = asrc[s0 * HEADS + head] + ad;
            ushort4 u0 = *reinterpret_cast<const ushort4*>(&Hb[(size_t)s0 * IN_FEAT + lane * 4]);
            float w0 = __expf((a0 > 0.f) ? a0 : NEG_SLOPE * a0);
            acc.x += w0 * bf2f(u0.x);
            acc.y += w0 * bf2f(u0.y);
            acc.z += w0 * bf2f(u0.z);
            acc.w += w0 * bf2f(u0.w);
            den += w0;
        }
        const float inv = 1.f / den;
        float4 r;
        r.x = fmaxf(acc.x * inv + bv.x, 0.f);
        r.y = fmaxf(acc.y * inv + bv.y, 0.f);
        r.z = fmaxf(acc.z * inv + bv.z, 0.f);
        r.w = fmaxf(acc.w * inv + bv.w, 0.f);
        *reinterpret_cast<float4*>(&out[(size_t)d * IN_FEAT + lane * 4]) = r;
    }
}

extern "C" void kernel_launch(void* const* d_in, const int* in_sizes, int n_in,
                              void* d_out, int out_size, void* d_ws, size_t ws_size,
                              hipStream_t stream) {
    const float* x       = (const float*)d_in[0];
    const int*   ei      = (const int*)d_in[1];      // harness converts int64 -> int32
    const float* W       = (const float*)d_in[2];
    const float* att_src = (const float*)d_in[3];
    const float* att_dst = (const float*)d_in[4];
    const float* bias    = (const float*)d_in[5];
    float*       out     = (float*)d_out;

    const int N = in_sizes[0] / IN_FEAT;   // 50000
    const int E = in_sizes[1] / 2;         // 800000
    const int Npad = (N + 63) & ~63;       // 50048

    // workspace layout
    unsigned short* Xb = (unsigned short*)d_ws;               // Npad*256 bf16
    unsigned short* Hb = Xb + (size_t)Npad * IN_FEAT;         // Npad*256 bf16
    float* asrc       = (float*)(Hb + (size_t)Npad * IN_FEAT);
    float* adst       = asrc + (size_t)N * HEADS;
    int*   counts     = (int*)(adst + (size_t)N * HEADS);
    int*   offsets    = counts + N;
    int*   cursor     = offsets + N;
    int*   sorted_src = cursor + N;                           // E
    int*   gcur       = sorted_src + E;                       // 4 ints
    unsigned short* Wtb = (unsigned short*)(gcur + 4);        // 256*256 bf16

    // CSR build
    zero_counts<<<256, 256, 0, stream>>>(counts, N, gcur);
    hist_kernel<<<2048, 256, 0, stream>>>(ei, counts, E, N);
    scan_atomic<<<(N + 1023) / 1024, 1024, 0, stream>>>(counts, offsets, cursor, gcur, N);
    scatter_kernel<<<2048, 256, 0, stream>>>(ei, cursor, sorted_src, E, N);

    // bf16 pre-convert (pre-swizzled) + projection + fused logits
    {
        int total = N * 32 + 256 * 32;
        cvt_xw<<<(total + 255) / 256, 256, 0, stream>>>(x, W, Xb, Wtb, N);
    }
    gemm_mfma<<<Npad / 64, 256, 0, stream>>>(Xb, Wtb, att_src, att_dst, Hb, asrc, adst, N);

    // gather aggregation (no atomics)
    aggregate<<<(N * 64 + 255) / 256, 256, 0, stream>>>(Hb, asrc, adst, offsets, counts,
                                                        sorted_src, bias, out, N);
}

// Round 10
// 222.581 us; speedup vs baseline: 1.0904x; 1.0886x over previous
//
#include <hip/hip_runtime.h>
#include <hip/hip_bf16.h>

#define IN_FEAT 256
#define HEADS 4
#define OUT_FEAT 64
#define NEG_SLOPE 0.2f

typedef __bf16 bf16x8 __attribute__((ext_vector_type(8)));
typedef float f32x4 __attribute__((ext_vector_type(4)));

__device__ inline unsigned short f2bf(float f) {
    union { float f; unsigned u; } v; v.f = f;
    unsigned r = v.u + 0x7FFF + ((v.u >> 16) & 1);   // RNE, finite inputs
    return (unsigned short)(r >> 16);
}
__device__ inline float bf2f(unsigned short u) {
    union { unsigned u; float f; } v; v.u = ((unsigned)u) << 16; return v.f;
}

// ---------------- CSR build --------------------------------------------------
__global__ void zero_counts(int* __restrict__ counts, int n, int* __restrict__ gcur) {
    int idx = blockIdx.x * blockDim.x + threadIdx.x;
    int stride = gridDim.x * blockDim.x;
    for (int i = idx; i < n; i += stride) counts[i] = 0;
    if (blockIdx.x == 0 && threadIdx.x == 0) *gcur = 0;
}

// ---------------- merged: hist (dst histogram) + X/W -> bf16 pre-swizzled ---
// blocks [0, nCvt): conversion; blocks [nCvt, grid): histogram.
__global__ void hist_cvt(const int* __restrict__ ei, int* __restrict__ counts,
                         const float* __restrict__ X, const float* __restrict__ W,
                         unsigned short* __restrict__ Xb, unsigned short* __restrict__ Wtb,
                         int E, int N, int nCvt) {
    const int tid = threadIdx.x;
    if ((int)blockIdx.x >= nCvt) {
        // ---- histogram ----
        int b = blockIdx.x - nCvt;
        int idx = b * 256 + tid;
        int stride = (gridDim.x - nCvt) * 256;
        for (int e = idx; e < E; e += stride) {
            int d = ei[E + e];
            if ((unsigned)d < (unsigned)N) atomicAdd(&counts[d], 1);
        }
        return;
    }
    // ---- conversion: chunk c (16B) of K-group g in row r stored at c ^ (r&7)
    const int totalX = N * 32;
    const int total = totalX + 256 * 32;
    int idx = blockIdx.x * 256 + tid;
    if (idx >= total) return;
    if (idx < totalX) {
        int r = idx >> 5, j = idx & 31;
        int g = j >> 3, c = j & 7;
        const float4 v0 = *reinterpret_cast<const float4*>(&X[(size_t)r * 256 + j * 8]);
        const float4 v1 = *reinterpret_cast<const float4*>(&X[(size_t)r * 256 + j * 8 + 4]);
        ushort4 p0, p1;
        p0.x = f2bf(v0.x); p0.y = f2bf(v0.y); p0.z = f2bf(v0.z); p0.w = f2bf(v0.w);
        p1.x = f2bf(v1.x); p1.y = f2bf(v1.y); p1.z = f2bf(v1.z); p1.w = f2bf(v1.w);
        unsigned short* dst = &Xb[(size_t)r * 256 + (g * 8 + (c ^ (r & 7))) * 8];
        *reinterpret_cast<ushort4*>(dst) = p0;
        *reinterpret_cast<ushort4*>(dst + 4) = p1;
    } else {
        int t = idx - totalX;
        int n = t >> 5, j = t & 31;
        int g = j >> 3, c = j & 7;
        ushort4 p0, p1;
        p0.x = f2bf(W[(size_t)(j * 8 + 0) * 256 + n]);
        p0.y = f2bf(W[(size_t)(j * 8 + 1) * 256 + n]);
        p0.z = f2bf(W[(size_t)(j * 8 + 2) * 256 + n]);
        p0.w = f2bf(W[(size_t)(j * 8 + 3) * 256 + n]);
        p1.x = f2bf(W[(size_t)(j * 8 + 4) * 256 + n]);
        p1.y = f2bf(W[(size_t)(j * 8 + 5) * 256 + n]);
        p1.z = f2bf(W[(size_t)(j * 8 + 6) * 256 + n]);
        p1.w = f2bf(W[(size_t)(j * 8 + 7) * 256 + n]);
        unsigned short* dst = &Wtb[(size_t)n * 256 + (g * 8 + (c ^ (n & 7))) * 8];
        *reinterpret_cast<ushort4*>(dst) = p0;
        *reinterpret_cast<ushort4*>(dst + 4) = p1;
    }
}

// Parallel scan: per-1024 tile local scan + one atomicAdd to reserve the base.
__global__ __launch_bounds__(1024) void scan_atomic(const int* __restrict__ counts,
                                                    int* __restrict__ offsets,
                                                    int* __restrict__ cursor,
                                                    int* __restrict__ gcur, int N) {
    __shared__ int sdata[1024];
    __shared__ int sbase;
    const int t = threadIdx.x;
    const int i = blockIdx.x * 1024 + t;
    const int v = (i < N) ? counts[i] : 0;
    sdata[t] = v;
    __syncthreads();
    for (int off = 1; off < 1024; off <<= 1) {
        int u = (t >= off) ? sdata[t - off] : 0;
        __syncthreads();
        sdata[t] += u;
        __syncthreads();
    }
    if (t == 1023) sbase = atomicAdd(gcur, sdata[1023]);
    __syncthreads();
    if (i < N) {
        int excl = sbase + sdata[t] - v;
        offsets[i] = excl;
        cursor[i] = excl;
    }
}

__global__ void scatter_kernel(const int* __restrict__ ei, int* __restrict__ cursor,
                               int* __restrict__ sorted_src, int E, int N) {
    int idx = blockIdx.x * blockDim.x + threadIdx.x;
    int stride = gridDim.x * blockDim.x;
    for (int e = idx; e < E; e += stride) {
        int s = ei[e];
        int d = ei[E + e];
        if ((unsigned)s >= (unsigned)N || (unsigned)d >= (unsigned)N) continue;
        int pos = atomicAdd(&cursor[d], 1);
        sorted_src[pos] = s;
    }
}

// ---------------- Hb = bf16(Xb @ Wtb^T), fused per-head logits --------------
// 128x256 tile, BK=64, 8 waves as 4(m)x2(n); wave-tile 32x128.
// LDS double-buffer + register prefetch DISTANCE 2: loads for K-step g+2
// issue at step g => counted vmcnt, never a full drain in steady state.
__global__ __launch_bounds__(512) void gemm_mfma(const unsigned short* __restrict__ Xb,
                                                 const unsigned short* __restrict__ Wtb,
                                                 const float* __restrict__ att_src,
                                                 const float* __restrict__ att_dst,
                                                 unsigned short* __restrict__ Hb,
                                                 float* __restrict__ asrc,
                                                 float* __restrict__ adst, int M) {
    __shared__ __align__(16) unsigned short sMem[2 * 24576];  // 96 KB: 2 bufs of (sA 16K + sB 32K)
    const int brow = blockIdx.x * 128;
    const int tid = threadIdx.x;
    const int lane = tid & 63;
    const int wid = tid >> 6;
    const int wr = wid >> 1;          // 0..3 (32-row slice)
    const int wc = wid & 1;           // 0..1 (128-col half = 2 heads)
    const uint4* Xb4 = reinterpret_cast<const uint4*>(Xb);
    const uint4* Wtb4 = reinterpret_cast<const uint4*>(Wtb);

    f32x4 acc[2][8] = {};
    uint4 pa0[2], pb0[4], pa1[2], pb1[4];

    // global loads for one K-step: row stride 32 uint4, K-group stride 8 uint4
#define LOADS(pa, pb, g)                                                          \
    {                                                                             \
        _Pragma("unroll")                                                         \
        for (int i = 0; i < 2; ++i) {                                             \
            int ci = i * 512 + tid;                                               \
            pa[i] = Xb4[(size_t)(brow + (ci >> 3)) * 32 + (g) * 8 + (ci & 7)];    \
        }                                                                         \
        _Pragma("unroll")                                                         \
        for (int j = 0; j < 4; ++j) {                                             \
            int ci = j * 512 + tid;                                               \
            pb[j] = Wtb4[(size_t)(ci >> 3) * 32 + (g) * 8 + (ci & 7)];            \
        }                                                                         \
    }

#define WRITE(par, pa, pb)                                                        \
    {                                                                             \
        uint4* dA = reinterpret_cast<uint4*>(sMem + (par) * 24576);               \
        uint4* dB = dA + 1024;                                                    \
        dA[tid] = pa[0];                                                          \
        dA[tid + 512] = pa[1];                                                    \
        _Pragma("unroll")                                                         \
        for (int j = 0; j < 4; ++j) dB[tid + j * 512] = pb[j];                    \
    }

#define COMPUTE(par)                                                              \
    {                                                                             \
        const unsigned short* sA = sMem + (par) * 24576;                          \
        const unsigned short* sB = sA + 8192;                                     \
        __builtin_amdgcn_s_setprio(1);                                            \
        _Pragma("unroll")                                                         \
        for (int kk = 0; kk < 2; ++kk) {                                          \
            bf16x8 af[2], bfr[8];                                                 \
            const int c = kk * 4 + (lane >> 4);                                   \
            _Pragma("unroll")                                                     \
            for (int m = 0; m < 2; ++m) {                                         \
                int r = wr * 32 + m * 16 + (lane & 15);                           \
                af[m] = *reinterpret_cast<const bf16x8*>(                         \
                    &sA[r * 64 + ((c ^ (r & 7)) << 3)]);                          \
            }                                                                     \
            _Pragma("unroll")                                                     \
            for (int nf = 0; nf < 8; ++nf) {                                      \
                int n = wc * 128 + nf * 16 + (lane & 15);                         \
                bfr[nf] = *reinterpret_cast<const bf16x8*>(                       \
                    &sB[n * 64 + ((c ^ (n & 7)) << 3)]);                          \
            }                                                                     \
            _Pragma("unroll")                                                     \
            for (int m = 0; m < 2; ++m)                                           \
                _Pragma("unroll")                                                 \
                for (int nf = 0; nf < 8; ++nf)                                    \
                    acc[m][nf] = __builtin_amdgcn_mfma_f32_16x16x32_bf16(         \
                        af[m], bfr[nf], acc[m][nf], 0, 0, 0);                     \
        }                                                                         \
        __builtin_amdgcn_s_setprio(0);                                            \
    }

    LOADS(pa0, pb0, 0);
    LOADS(pa1, pb1, 1);
    // g=0
    WRITE(0, pa0, pb0);           // compiler waits only pa0/pb0 (vmcnt counted)
    LOADS(pa0, pb0, 2);
    __syncthreads();
    COMPUTE(0);
    // g=1
    __syncthreads();
    WRITE(1, pa1, pb1);
    LOADS(pa1, pb1, 3);
    __syncthreads();
    COMPUTE(1);
    // g=2
    __syncthreads();
    WRITE(0, pa0, pb0);
    __syncthreads();
    COMPUTE(0);
    // g=3
    __syncthreads();
    WRITE(1, pa1, pb1);
    __syncthreads();
    COMPUTE(1);
#undef LOADS
#undef WRITE
#undef COMPUTE

    // ---- fused logits from fragments (register-only + shuffles) ----
    float attS[8], attD[8];
#pragma unroll
    for (int nf = 0; nf < 8; ++nf) {
        int col = wc * 128 + nf * 16 + (lane & 15);
        attS[nf] = att_src[col];
        attD[nf] = att_dst[col];
    }
    __syncthreads();   // all LDS reads done; sC may overwrite buffers
    unsigned short* sC = sMem;    // 128 x 256 bf16 = 64 KB
#pragma unroll
    for (int m = 0; m < 2; ++m)
#pragma unroll
        for (int i = 0; i < 4; ++i) {
            int rl = wr * 32 + m * 16 + ((lane >> 4) << 2) + i;   // local row
            int R = brow + rl;
            float p0s = 0.f, p0d = 0.f, p1s = 0.f, p1d = 0.f;
            const int swz = (rl >> 2) & 3;
#pragma unroll
            for (int nf = 0; nf < 8; ++nf) {
                float v = acc[m][nf][i];
                if (nf < 4) { p0s += v * attS[nf]; p0d += v * attD[nf]; }
                else        { p1s += v * attS[nf]; p1d += v * attD[nf]; }
                int chunk = wc * 8 + nf;              // 32B chunks, swizzled
                sC[rl * 256 + ((chunk ^ swz) << 4) + (lane & 15)] = f2bf(v);
            }
#pragma unroll
            for (int off = 1; off < 16; off <<= 1) {
                p0s += __shfl_xor(p0s, off, 64);
                p0d += __shfl_xor(p0d, off, 64);
                p1s += __shfl_xor(p1s, off, 64);
                p1d += __shfl_xor(p1d, off, 64);
            }
            if ((lane & 15) == 0 && R < M) {
                int h0 = wc * 2;
                asrc[R * HEADS + h0]     = p0s;
                asrc[R * HEADS + h0 + 1] = p1s;
                adst[R * HEADS + h0]     = p0d;
                adst[R * HEADS + h0 + 1] = p1d;
            }
        }
    __syncthreads();
    // ---- coalesced store: full 512B rows ----
#pragma unroll
    for (int it = 0; it < 8; ++it) {
        int gc = it * 512 + tid;          // 16B chunk id, 32 per row
        int r = gc >> 5;
        int j = gc & 31;
        int cs = (j >> 1) ^ ((r >> 2) & 3);
        const uint4 v = *reinterpret_cast<const uint4*>(
            &sC[r * 256 + (cs << 4) + (j & 1) * 8]);
        if (brow + r < M)
            *reinterpret_cast<uint4*>(&Hb[(size_t)(brow + r) * 256 + j * 8]) = v;
    }
}

// ---------------- gather aggregate: one wave per destination node -----------
__global__ __launch_bounds__(256) void aggregate(const unsigned short* __restrict__ Hb,
                                                 const float* __restrict__ asrc,
                                                 const float* __restrict__ adst,
                                                 const int* __restrict__ offsets,
                                                 const int* __restrict__ counts,
                                                 const int* __restrict__ sorted_src,
                                                 const float* __restrict__ bias,
                                                 float* __restrict__ out, int N) {
    int gtid = blockIdx.x * blockDim.x + threadIdx.x;
    int wave = gtid >> 6;
    int lane = threadIdx.x & 63;
    int nwaves = (gridDim.x * blockDim.x) >> 6;
    int head = lane >> 4;
    const float4 bv = *reinterpret_cast<const float4*>(&bias[lane * 4]);
    for (int d = wave; d < N; d += nwaves) {
        const float ad = adst[d * HEADS + head];
        float a = asrc[d * HEADS + head] + ad;
        float w = __expf((a > 0.f) ? a : NEG_SLOPE * a);
        ushort4 ud = *reinterpret_cast<const ushort4*>(&Hb[(size_t)d * IN_FEAT + lane * 4]);
        float4 acc = make_float4(w * bf2f(ud.x), w * bf2f(ud.y),
                                 w * bf2f(ud.z), w * bf2f(ud.w));
        float den = w;
        const int start = offsets[d];
        const int cnt = counts[d];
        int k = 0;
        for (; k + 3 < cnt; k += 4) {
            int s0 = sorted_src[start + k + 0];
            int s1 = sorted_src[start + k + 1];
            int s2 = sorted_src[start + k + 2];
            int s3 = sorted_src[start + k + 3];
            float a0 = asrc[s0 * HEADS + head] + ad;
            float a1 = asrc[s1 * HEADS + head] + ad;
            float a2 = asrc[s2 * HEADS + head] + ad;
            float a3 = asrc[s3 * HEADS + head] + ad;
            ushort4 u0 = *reinterpret_cast<const ushort4*>(&Hb[(size_t)s0 * IN_FEAT + lane * 4]);
            ushort4 u1 = *reinterpret_cast<const ushort4*>(&Hb[(size_t)s1 * IN_FEAT + lane * 4]);
            ushort4 u2 = *reinterpret_cast<const ushort4*>(&Hb[(size_t)s2 * IN_FEAT + lane * 4]);
            ushort4 u3 = *reinterpret_cast<const ushort4*>(&Hb[(size_t)s3 * IN_FEAT + lane * 4]);
            float w0 = __expf((a0 > 0.f) ? a0 : NEG_SLOPE * a0);
            float w1 = __expf((a1 > 0.f) ? a1 : NEG_SLOPE * a1);
            float w2 = __expf((a2 > 0.f) ? a2 : NEG_SLOPE * a2);
            float w3 = __expf((a3 > 0.f) ? a3 : NEG_SLOPE * a3);
            acc.x += w0 * bf2f(u0.x) + w1 * bf2f(u1.x) + w2 * bf2f(u2.x) + w3 * bf2f(u3.x);
            acc.y += w0 * bf2f(u0.y) + w1 * bf2f(u1.y) + w2 * bf2f(u2.y) + w3 * bf2f(u3.y);
            acc.z += w0 * bf2f(u0.z) + w1 * bf2f(u1.z) + w2 * bf2f(u2.z) + w3 * bf2f(u3.z);
            acc.w += w0 * bf2f(u0.w) + w1 * bf2f(u1.w) + w2 * bf2f(u2.w) + w3 * bf2f(u3.w);
            den += w0 + w1 + w2 + w3;
        }
        for (; k < cnt; ++k) {
            int s0 = sorted_src[start + k];
            float a0 = asrc[s0 * HEADS + head] + ad;
            ushort4 u0 = *reinterpret_cast<const ushort4*>(&Hb[(size_t)s0 * IN_FEAT + lane * 4]);
            float w0 = __expf((a0 > 0.f) ? a0 : NEG_SLOPE * a0);
            acc.x += w0 * bf2f(u0.x);
            acc.y += w0 * bf2f(u0.y);
            acc.z += w0 * bf2f(u0.z);
            acc.w += w0 * bf2f(u0.w);
            den += w0;
        }
        const float inv = 1.f / den;
        float4 r;
        r.x = fmaxf(acc.x * inv + bv.x, 0.f);
        r.y = fmaxf(acc.y * inv + bv.y, 0.f);
        r.z = fmaxf(acc.z * inv + bv.z, 0.f);
        r.w = fmaxf(acc.w * inv + bv.w, 0.f);
        *reinterpret_cast<float4*>(&out[(size_t)d * IN_FEAT + lane * 4]) = r;
    }
}

extern "C" void kernel_launch(void* const* d_in, const int* in_sizes, int n_in,
                              void* d_out, int out_size, void* d_ws, size_t ws_size,
                              hipStream_t stream) {
    const float* x       = (const float*)d_in[0];
    const int*   ei      = (const int*)d_in[1];      // harness converts int64 -> int32
    const float* W       = (const float*)d_in[2];
    const float* att_src = (const float*)d_in[3];
    const float* att_dst = (const float*)d_in[4];
    const float* bias    = (const float*)d_in[5];
    float*       out     = (float*)d_out;

    const int N = in_sizes[0] / IN_FEAT;   // 50000
    const int E = in_sizes[1] / 2;         // 800000
    const int Npad = (N + 127) & ~127;     // 50048 (= 391 * 128)

    // workspace layout
    unsigned short* Xb = (unsigned short*)d_ws;               // Npad*256 bf16
    unsigned short* Hb = Xb + (size_t)Npad * IN_FEAT;         // Npad*256 bf16
    float* asrc       = (float*)(Hb + (size_t)Npad * IN_FEAT);
    float* adst       = asrc + (size_t)N * HEADS;
    int*   counts     = (int*)(adst + (size_t)N * HEADS);
    int*   offsets    = counts + N;
    int*   cursor     = offsets + N;
    int*   sorted_src = cursor + N;                           // E
    int*   gcur       = sorted_src + E;                       // 4 ints (align)
    unsigned short* Wtb = (unsigned short*)(gcur + 4);        // 256*256 bf16

    zero_counts<<<256, 256, 0, stream>>>(counts, N, gcur);

    // hist (dst histogram) || X/W bf16 pre-convert — independent, one kernel
    {
        int nCvt = (N * 32 + 256 * 32 + 255) / 256;
        hist_cvt<<<nCvt + 1024, 256, 0, stream>>>(ei, counts, x, W, Xb, Wtb, E, N, nCvt);
    }
    scan_atomic<<<(N + 1023) / 1024, 1024, 0, stream>>>(counts, offsets, cursor, gcur, N);
    scatter_kernel<<<2048, 256, 0, stream>>>(ei, cursor, sorted_src, E, N);

    gemm_mfma<<<Npad / 128, 512, 0, stream>>>(Xb, Wtb, att_src, att_dst, Hb, asrc, adst, N);

    aggregate<<<(N * 64 + 255) / 256, 256, 0, stream>>>(Hb, asrc, adst, offsets, counts,
                                                        sorted_src, bias, out, N);
}

// Round 11
// 197.397 us; speedup vs baseline: 1.2295x; 1.1276x over previous
//
#include <hip/hip_runtime.h>
#include <hip/hip_bf16.h>

#define IN_FEAT 256
#define HEADS 4
#define OUT_FEAT 64
#define NEG_SLOPE 0.2f

typedef __bf16 bf16x8 __attribute__((ext_vector_type(8)));
typedef float f32x4 __attribute__((ext_vector_type(4)));

__device__ inline unsigned short f2bf(float f) {
    union { float f; unsigned u; } v; v.f = f;
    unsigned r = v.u + 0x7FFF + ((v.u >> 16) & 1);   // RNE, finite inputs
    return (unsigned short)(r >> 16);
}
__device__ inline float bf2f(unsigned short u) {
    union { unsigned u; float f; } v; v.u = ((unsigned)u) << 16; return v.f;
}

// ---------------- merged: hist (dst histogram) + X/W -> bf16 pre-swizzled ---
// blocks [0, nCvt): conversion; blocks [nCvt, grid): histogram.
__global__ void hist_cvt(const int* __restrict__ ei, int* __restrict__ counts,
                         const float* __restrict__ X, const float* __restrict__ W,
                         unsigned short* __restrict__ Xb, unsigned short* __restrict__ Wtb,
                         int E, int N, int nCvt) {
    const int tid = threadIdx.x;
    if ((int)blockIdx.x >= nCvt) {
        int b = blockIdx.x - nCvt;
        int idx = b * 256 + tid;
        int stride = (gridDim.x - nCvt) * 256;
        for (int e = idx; e < E; e += stride) {
            int d = ei[E + e];
            if ((unsigned)d < (unsigned)N) atomicAdd(&counts[d], 1);
        }
        return;
    }
    const int totalX = N * 32;
    const int total = totalX + 256 * 32;
    int idx = blockIdx.x * 256 + tid;
    if (idx >= total) return;
    if (idx < totalX) {
        int r = idx >> 5, j = idx & 31;
        int g = j >> 3, c = j & 7;
        const float4 v0 = *reinterpret_cast<const float4*>(&X[(size_t)r * 256 + j * 8]);
        const float4 v1 = *reinterpret_cast<const float4*>(&X[(size_t)r * 256 + j * 8 + 4]);
        ushort4 p0, p1;
        p0.x = f2bf(v0.x); p0.y = f2bf(v0.y); p0.z = f2bf(v0.z); p0.w = f2bf(v0.w);
        p1.x = f2bf(v1.x); p1.y = f2bf(v1.y); p1.z = f2bf(v1.z); p1.w = f2bf(v1.w);
        unsigned short* dst = &Xb[(size_t)r * 256 + (g * 8 + (c ^ (r & 7))) * 8];
        *reinterpret_cast<ushort4*>(dst) = p0;
        *reinterpret_cast<ushort4*>(dst + 4) = p1;
    } else {
        int t = idx - totalX;
        int n = t >> 5, j = t & 31;
        int g = j >> 3, c = j & 7;
        ushort4 p0, p1;
        p0.x = f2bf(W[(size_t)(j * 8 + 0) * 256 + n]);
        p0.y = f2bf(W[(size_t)(j * 8 + 1) * 256 + n]);
        p0.z = f2bf(W[(size_t)(j * 8 + 2) * 256 + n]);
        p0.w = f2bf(W[(size_t)(j * 8 + 3) * 256 + n]);
        p1.x = f2bf(W[(size_t)(j * 8 + 4) * 256 + n]);
        p1.y = f2bf(W[(size_t)(j * 8 + 5) * 256 + n]);
        p1.z = f2bf(W[(size_t)(j * 8 + 6) * 256 + n]);
        p1.w = f2bf(W[(size_t)(j * 8 + 7) * 256 + n]);
        unsigned short* dst = &Wtb[(size_t)n * 256 + (g * 8 + (c ^ (n & 7))) * 8];
        *reinterpret_cast<ushort4*>(dst) = p0;
        *reinterpret_cast<ushort4*>(dst + 4) = p1;
    }
}

// Parallel scan: per-1024 tile local scan + one atomicAdd to reserve the base.
__global__ __launch_bounds__(1024) void scan_atomic(const int* __restrict__ counts,
                                                    int* __restrict__ offsets,
                                                    int* __restrict__ cursor,
                                                    int* __restrict__ gcur, int N) {
    __shared__ int sdata[1024];
    __shared__ int sbase;
    const int t = threadIdx.x;
    const int i = blockIdx.x * 1024 + t;
    const int v = (i < N) ? counts[i] : 0;
    sdata[t] = v;
    __syncthreads();
    for (int off = 1; off < 1024; off <<= 1) {
        int u = (t >= off) ? sdata[t - off] : 0;
        __syncthreads();
        sdata[t] += u;
        __syncthreads();
    }
    if (t == 1023) sbase = atomicAdd(gcur, sdata[1023]);
    __syncthreads();
    if (i < N) {
        int excl = sbase + sdata[t] - v;
        offsets[i] = excl;
        cursor[i] = excl;
    }
}

// ---------------- merged: GEMM (blocks [0,NG)) + edge scatter (rest) --------
// GEMM: 128x256 tile, BK=64, 8 waves 4(m)x2(n), LDS dbuf, prefetch distance 2.
// Scatter blocks backfill CUs during the GEMM tail (both independent).
__global__ __launch_bounds__(512) void gemm_scatter(const unsigned short* __restrict__ Xb,
                                                    const unsigned short* __restrict__ Wtb,
                                                    const float* __restrict__ att_src,
                                                    const float* __restrict__ att_dst,
                                                    unsigned short* __restrict__ Hb,
                                                    float* __restrict__ asrc,
                                                    float* __restrict__ adst, int M,
                                                    const int* __restrict__ ei,
                                                    int* __restrict__ cursor,
                                                    int* __restrict__ sorted_src,
                                                    int E, int N, int NG) {
    __shared__ __align__(16) unsigned short sMem[2 * 24576];  // 96 KB
    const int tid = threadIdx.x;
    if ((int)blockIdx.x >= NG) {
        // ---- scatter: src ids into dst-sorted order ----
        int idx = (blockIdx.x - NG) * 512 + tid;
        int stride = (gridDim.x - NG) * 512;
        for (int e = idx; e < E; e += stride) {
            int s = ei[e];
            int d = ei[E + e];
            if ((unsigned)s >= (unsigned)N || (unsigned)d >= (unsigned)N) continue;
            int pos = atomicAdd(&cursor[d], 1);
            sorted_src[pos] = s;
        }
        return;
    }
    const int brow = blockIdx.x * 128;
    const int lane = tid & 63;
    const int wid = tid >> 6;
    const int wr = wid >> 1;          // 0..3 (32-row slice)
    const int wc = wid & 1;           // 0..1 (128-col half = 2 heads)
    const uint4* Xb4 = reinterpret_cast<const uint4*>(Xb);
    const uint4* Wtb4 = reinterpret_cast<const uint4*>(Wtb);

    f32x4 acc[2][8] = {};
    uint4 pa0[2], pb0[4], pa1[2], pb1[4];

#define LOADS(pa, pb, g)                                                          \
    {                                                                             \
        _Pragma("unroll")                                                         \
        for (int i = 0; i < 2; ++i) {                                             \
            int ci = i * 512 + tid;                                               \
            pa[i] = Xb4[(size_t)(brow + (ci >> 3)) * 32 + (g) * 8 + (ci & 7)];    \
        }                                                                         \
        _Pragma("unroll")                                                         \
        for (int j = 0; j < 4; ++j) {                                             \
            int ci = j * 512 + tid;                                               \
            pb[j] = Wtb4[(size_t)(ci >> 3) * 32 + (g) * 8 + (ci & 7)];            \
        }                                                                         \
    }

#define WRITE(par, pa, pb)                                                        \
    {                                                                             \
        uint4* dA = reinterpret_cast<uint4*>(sMem + (par) * 24576);               \
        uint4* dB = dA + 1024;                                                    \
        dA[tid] = pa[0];                                                          \
        dA[tid + 512] = pa[1];                                                    \
        _Pragma("unroll")                                                         \
        for (int j = 0; j < 4; ++j) dB[tid + j * 512] = pb[j];                    \
    }

#define COMPUTE(par)                                                              \
    {                                                                             \
        const unsigned short* sA = sMem + (par) * 24576;                          \
        const unsigned short* sB = sA + 8192;                                     \
        __builtin_amdgcn_s_setprio(1);                                            \
        _Pragma("unroll")                                                         \
        for (int kk = 0; kk < 2; ++kk) {                                          \
            bf16x8 af[2], bfr[8];                                                 \
            const int c = kk * 4 + (lane >> 4);                                   \
            _Pragma("unroll")                                                     \
            for (int m = 0; m < 2; ++m) {                                         \
                int r = wr * 32 + m * 16 + (lane & 15);                           \
                af[m] = *reinterpret_cast<const bf16x8*>(                         \
                    &sA[r * 64 + ((c ^ (r & 7)) << 3)]);                          \
            }                                                                     \
            _Pragma("unroll")                                                     \
            for (int nf = 0; nf < 8; ++nf) {                                      \
                int n = wc * 128 + nf * 16 + (lane & 15);                         \
                bfr[nf] = *reinterpret_cast<const bf16x8*>(                       \
                    &sB[n * 64 + ((c ^ (n & 7)) << 3)]);                          \
            }                                                                     \
            _Pragma("unroll")                                                     \
            for (int m = 0; m < 2; ++m)                                           \
                _Pragma("unroll")                                                 \
                for (int nf = 0; nf < 8; ++nf)                                    \
                    acc[m][nf] = __builtin_amdgcn_mfma_f32_16x16x32_bf16(         \
                        af[m], bfr[nf], acc[m][nf], 0, 0, 0);                     \
        }                                                                         \
        __builtin_amdgcn_s_setprio(0);                                            \
    }

    LOADS(pa0, pb0, 0);
    LOADS(pa1, pb1, 1);
    WRITE(0, pa0, pb0);
    LOADS(pa0, pb0, 2);
    __syncthreads();
    COMPUTE(0);
    __syncthreads();
    WRITE(1, pa1, pb1);
    LOADS(pa1, pb1, 3);
    __syncthreads();
    COMPUTE(1);
    __syncthreads();
    WRITE(0, pa0, pb0);
    __syncthreads();
    COMPUTE(0);
    __syncthreads();
    WRITE(1, pa1, pb1);
    __syncthreads();
    COMPUTE(1);
#undef LOADS
#undef WRITE
#undef COMPUTE

    // ---- fused logits from fragments ----
    float attS[8], attD[8];
#pragma unroll
    for (int nf = 0; nf < 8; ++nf) {
        int col = wc * 128 + nf * 16 + (lane & 15);
        attS[nf] = att_src[col];
        attD[nf] = att_dst[col];
    }
    __syncthreads();   // all LDS reads done; sC may overwrite buffers
    unsigned short* sC = sMem;    // 128 x 256 bf16 = 64 KB
#pragma unroll
    for (int m = 0; m < 2; ++m)
#pragma unroll
        for (int i = 0; i < 4; ++i) {
            int rl = wr * 32 + m * 16 + ((lane >> 4) << 2) + i;   // local row
            int R = brow + rl;
            float p0s = 0.f, p0d = 0.f, p1s = 0.f, p1d = 0.f;
            const int swz = (rl >> 2) & 3;
#pragma unroll
            for (int nf = 0; nf < 8; ++nf) {
                float v = acc[m][nf][i];
                if (nf < 4) { p0s += v * attS[nf]; p0d += v * attD[nf]; }
                else        { p1s += v * attS[nf]; p1d += v * attD[nf]; }
                int chunk = wc * 8 + nf;              // 32B chunks, swizzled
                sC[rl * 256 + ((chunk ^ swz) << 4) + (lane & 15)] = f2bf(v);
            }
#pragma unroll
            for (int off = 1; off < 16; off <<= 1) {
                p0s += __shfl_xor(p0s, off, 64);
                p0d += __shfl_xor(p0d, off, 64);
                p1s += __shfl_xor(p1s, off, 64);
                p1d += __shfl_xor(p1d, off, 64);
            }
            if ((lane & 15) == 0 && R < M) {
                int h0 = wc * 2;
                asrc[R * HEADS + h0]     = p0s;
                asrc[R * HEADS + h0 + 1] = p1s;
                adst[R * HEADS + h0]     = p0d;
                adst[R * HEADS + h0 + 1] = p1d;
            }
        }
    __syncthreads();
    // ---- coalesced store: full 512B rows ----
#pragma unroll
    for (int it = 0; it < 8; ++it) {
        int gc = it * 512 + tid;          // 16B chunk id, 32 per row
        int r = gc >> 5;
        int j = gc & 31;
        int cs = (j >> 1) ^ ((r >> 2) & 3);
        const uint4 v = *reinterpret_cast<const uint4*>(
            &sC[r * 256 + (cs << 4) + (j & 1) * 8]);
        if (brow + r < M)
            *reinterpret_cast<uint4*>(&Hb[(size_t)(brow + r) * 256 + j * 8]) = v;
    }
}

// ---------------- gather aggregate: one wave per destination node -----------
__global__ __launch_bounds__(256) void aggregate(const unsigned short* __restrict__ Hb,
                                                 const float* __restrict__ asrc,
                                                 const float* __restrict__ adst,
                                                 const int* __restrict__ offsets,
                                                 const int* __restrict__ counts,
                                                 const int* __restrict__ sorted_src,
                                                 const float* __restrict__ bias,
                                                 float* __restrict__ out, int N) {
    int gtid = blockIdx.x * blockDim.x + threadIdx.x;
    int wave = gtid >> 6;
    int lane = threadIdx.x & 63;
    int nwaves = (gridDim.x * blockDim.x) >> 6;
    int head = lane >> 4;
    const float4 bv = *reinterpret_cast<const float4*>(&bias[lane * 4]);
    for (int d = wave; d < N; d += nwaves) {
        const float ad = adst[d * HEADS + head];
        float a = asrc[d * HEADS + head] + ad;
        float w = __expf((a > 0.f) ? a : NEG_SLOPE * a);
        ushort4 ud = *reinterpret_cast<const ushort4*>(&Hb[(size_t)d * IN_FEAT + lane * 4]);
        float4 acc = make_float4(w * bf2f(ud.x), w * bf2f(ud.y),
                                 w * bf2f(ud.z), w * bf2f(ud.w));
        float den = w;
        const int start = offsets[d];
        const int cnt = counts[d];
        int k = 0;
        for (; k + 3 < cnt; k += 4) {
            int s0 = sorted_src[start + k + 0];
            int s1 = sorted_src[start + k + 1];
            int s2 = sorted_src[start + k + 2];
            int s3 = sorted_src[start + k + 3];
            float a0 = asrc[s0 * HEADS + head] + ad;
            float a1 = asrc[s1 * HEADS + head] + ad;
            float a2 = asrc[s2 * HEADS + head] + ad;
            float a3 = asrc[s3 * HEADS + head] + ad;
            ushort4 u0 = *reinterpret_cast<const ushort4*>(&Hb[(size_t)s0 * IN_FEAT + lane * 4]);
            ushort4 u1 = *reinterpret_cast<const ushort4*>(&Hb[(size_t)s1 * IN_FEAT + lane * 4]);
            ushort4 u2 = *reinterpret_cast<const ushort4*>(&Hb[(size_t)s2 * IN_FEAT + lane * 4]);
            ushort4 u3 = *reinterpret_cast<const ushort4*>(&Hb[(size_t)s3 * IN_FEAT + lane * 4]);
            float w0 = __expf((a0 > 0.f) ? a0 : NEG_SLOPE * a0);
            float w1 = __expf((a1 > 0.f) ? a1 : NEG_SLOPE * a1);
            float w2 = __expf((a2 > 0.f) ? a2 : NEG_SLOPE * a2);
            float w3 = __expf((a3 > 0.f) ? a3 : NEG_SLOPE * a3);
            acc.x += w0 * bf2f(u0.x) + w1 * bf2f(u1.x) + w2 * bf2f(u2.x) + w3 * bf2f(u3.x);
            acc.y += w0 * bf2f(u0.y) + w1 * bf2f(u1.y) + w2 * bf2f(u2.y) + w3 * bf2f(u3.y);
            acc.z += w0 * bf2f(u0.z) + w1 * bf2f(u1.z) + w2 * bf2f(u2.z) + w3 * bf2f(u3.z);
            acc.w += w0 * bf2f(u0.w) + w1 * bf2f(u1.w) + w2 * bf2f(u2.w) + w3 * bf2f(u3.w);
            den += w0 + w1 + w2 + w3;
        }
        for (; k < cnt; ++k) {
            int s0 = sorted_src[start + k];
            float a0 = asrc[s0 * HEADS + head] + ad;
            ushort4 u0 = *reinterpret_cast<const ushort4*>(&Hb[(size_t)s0 * IN_FEAT + lane * 4]);
            float w0 = __expf((a0 > 0.f) ? a0 : NEG_SLOPE * a0);
            acc.x += w0 * bf2f(u0.x);
            acc.y += w0 * bf2f(u0.y);
            acc.z += w0 * bf2f(u0.z);
            acc.w += w0 * bf2f(u0.w);
            den += w0;
        }
        const float inv = 1.f / den;
        float4 r;
        r.x = fmaxf(acc.x * inv + bv.x, 0.f);
        r.y = fmaxf(acc.y * inv + bv.y, 0.f);
        r.z = fmaxf(acc.z * inv + bv.z, 0.f);
        r.w = fmaxf(acc.w * inv + bv.w, 0.f);
        *reinterpret_cast<float4*>(&out[(size_t)d * IN_FEAT + lane * 4]) = r;
    }
}

extern "C" void kernel_launch(void* const* d_in, const int* in_sizes, int n_in,
                              void* d_out, int out_size, void* d_ws, size_t ws_size,
                              hipStream_t stream) {
    const float* x       = (const float*)d_in[0];
    const int*   ei      = (const int*)d_in[1];      // harness converts int64 -> int32
    const float* W       = (const float*)d_in[2];
    const float* att_src = (const float*)d_in[3];
    const float* att_dst = (const float*)d_in[4];
    const float* bias    = (const float*)d_in[5];
    float*       out     = (float*)d_out;

    const int N = in_sizes[0] / IN_FEAT;   // 50000
    const int E = in_sizes[1] / 2;         // 800000
    const int Npad = (N + 127) & ~127;     // 50048

    // workspace layout
    unsigned short* Xb = (unsigned short*)d_ws;               // Npad*256 bf16
    unsigned short* Hb = Xb + (size_t)Npad * IN_FEAT;         // Npad*256 bf16
    float* asrc       = (float*)(Hb + (size_t)Npad * IN_FEAT);
    float* adst       = asrc + (size_t)N * HEADS;
    int*   counts     = (int*)(adst + (size_t)N * HEADS);
    int*   offsets    = counts + N;
    int*   cursor     = offsets + N;
    int*   sorted_src = cursor + N;                           // E
    int*   gcur       = sorted_src + E;                       // 4 ints (align)
    unsigned short* Wtb = (unsigned short*)(gcur + 4);        // 256*256 bf16

    // zero counts + global cursor via async memset (graph-capture legal)
    hipMemsetAsync(counts, 0, (size_t)N * sizeof(int), stream);
    hipMemsetAsync(gcur, 0, 4 * sizeof(int), stream);

    // hist (dst histogram) || X/W bf16 pre-convert — independent, one kernel
    {
        int nCvt = (N * 32 + 256 * 32 + 255) / 256;
        hist_cvt<<<nCvt + 1024, 256, 0, stream>>>(ei, counts, x, W, Xb, Wtb, E, N, nCvt);
    }
    scan_atomic<<<(N + 1023) / 1024, 1024, 0, stream>>>(counts, offsets, cursor, gcur, N);

    // GEMM (+fused logits) || edge scatter — independent, one kernel;
    // scatter blocks backfill the GEMM's scheduling tail.
    {
        int NG = Npad / 128;      // 391 gemm blocks
        int NS = 384;             // scatter blocks
        gemm_scatter<<<NG + NS, 512, 0, stream>>>(Xb, Wtb, att_src, att_dst,
                                                  Hb, asrc, adst, N,
                                                  ei, cursor, sorted_src, E, N, NG);
    }

    aggregate<<<(N * 64 + 255) / 256, 256, 0, stream>>>(Hb, asrc, adst, offsets, counts,
                                                        sorted_src, bias, out, N);
}